// Round 18
// baseline (1027.636 us; speedup 1.0000x reference)
//
#include <hip/hip_runtime.h>
#include <hip/hip_bf16.h>
#include <math.h>

#define V_SZ 50257
#define V_PAD 50304
#define E_SZ 512
#define H_N 8
#define L_N 8
#define HID_SZ 1365
#define HID_PAD 1408
#define T_SZ 1024
#define B_SZ 2
#define HD_SZ 64
#define ROWS (B_SZ * T_SZ)   // 2048

typedef short bf16x8 __attribute__((ext_vector_type(8)));
typedef float f32x4 __attribute__((ext_vector_type(4)));
typedef float f32x16 __attribute__((ext_vector_type(16)));

// ---------------------------------------------------------------------------
// Embedding + LN-stats epilogue
// ---------------------------------------------------------------------------
__global__ __launch_bounds__(128) void embed_kernel(
    const int* __restrict__ idx, const float* __restrict__ W,
    const float* __restrict__ P, float* __restrict__ x,
    float* __restrict__ stats) {
  const int bt = blockIdx.x;
  const int t = bt & (T_SZ - 1);
  const int id = idx[bt];
  const int e = threadIdx.x * 4;
  float4 w = *(const float4*)(W + (size_t)id * E_SZ + e);
  float4 p = *(const float4*)(P + (size_t)t * E_SZ + e);
  float4 r;
  r.x = w.x + p.x; r.y = w.y + p.y; r.z = w.z + p.z; r.w = w.w + p.w;
  *(float4*)(x + (size_t)bt * E_SZ + e) = r;
  float s = r.x + r.y + r.z + r.w;
  float q = r.x * r.x + r.y * r.y + r.z * r.z + r.w * r.w;
#pragma unroll
  for (int o = 32; o; o >>= 1) { s += __shfl_xor(s, o); q += __shfl_xor(q, o); }
  __shared__ float sr[4];
  if ((threadIdx.x & 63) == 0) {
    sr[(threadIdx.x >> 6) * 2] = s;
    sr[(threadIdx.x >> 6) * 2 + 1] = q;
  }
  __syncthreads();
  if (threadIdx.x < 16) {
    float a = (threadIdx.x == 0) ? sr[0] + sr[2] : 0.f;
    float b2 = (threadIdx.x == 0) ? sr[1] + sr[3] : 0.f;
    float* st = stats + (size_t)bt * 32 + threadIdx.x * 2;
    st[0] = a; st[1] = b2;
  }
}

// ---------------------------------------------------------------------------
// LN from precomputed stats: h_bf = LN(x) (final LN before head)
// ---------------------------------------------------------------------------
__global__ __launch_bounds__(256) void ln_from_stats(
    const float* __restrict__ x, const float* __restrict__ stats,
    const float* __restrict__ gamma, const float* __restrict__ beta,
    __hip_bfloat16* __restrict__ out) {
  const int row = blockIdx.x;
  const int tid = threadIdx.x;
  const float* sp = stats + (size_t)row * 32;
  float sum = 0.f, ssq = 0.f;
#pragma unroll
  for (int i = 0; i < 8; ++i) {
    float4 v = ((const float4*)sp)[i];
    sum += v.x + v.z; ssq += v.y + v.w;
  }
  const float mean = sum * (1.f / 512.f);
  const float var = ssq * (1.f / 512.f) - mean * mean;
  const float rstd = rsqrtf(var + 1e-5f);
  const float2 v = *(const float2*)(x + (size_t)row * E_SZ + tid * 2);
  const float2 sv = *(const float2*)(gamma + tid * 2);
  const float2 bv = *(const float2*)(beta + tid * 2);
  __hip_bfloat162 ov;
  ov.x = __float2bfloat16((v.x - mean) * rstd * sv.x + bv.x);
  ov.y = __float2bfloat16((v.y - mean) * rstd * sv.y + bv.y);
  *(__hip_bfloat162*)(out + (size_t)row * E_SZ + tid * 2) = ov;
}

// ---------------------------------------------------------------------------
// W_emb f32 -> bf16 (padded rows)
// ---------------------------------------------------------------------------
__global__ __launch_bounds__(256) void convert_wemb(
    const float* __restrict__ W, __hip_bfloat16* __restrict__ Wb) {
  const int tid = blockIdx.x * 256 + threadIdx.x;
  const int row = tid >> 6;
  const int c = (tid & 63) * 8;
  union { __hip_bfloat16 h[8]; int4 v; } u;
  if (row < V_SZ) {
    const float* p = W + (size_t)row * E_SZ + c;
#pragma unroll
    for (int j = 0; j < 8; ++j) u.h[j] = __float2bfloat16(p[j]);
  } else {
#pragma unroll
    for (int j = 0; j < 8; ++j) u.h[j] = __float2bfloat16(0.f);
  }
  *(int4*)(Wb + (size_t)row * E_SZ + c) = u.v;
}

// ---------------------------------------------------------------------------
// Batched transpose+convert [L][K][N] f32 -> [L][Npad][Kpad] bf16
// ---------------------------------------------------------------------------
__global__ __launch_bounds__(256) void transp_convert(
    const float* __restrict__ in, __hip_bfloat16* __restrict__ out,
    int K, int N, int Kpad, int Npad) {
  __shared__ float tile[32][33];
  const int l = blockIdx.z;
  in  += (size_t)l * K * N;
  out += (size_t)l * Npad * Kpad;
  const int tx = threadIdx.x & 31, ty = threadIdx.x >> 5;
  const int n0 = blockIdx.x * 32, k0 = blockIdx.y * 32;
#pragma unroll
  for (int i = 0; i < 4; ++i) {
    const int k = k0 + ty + i * 8, n = n0 + tx;
    tile[ty + i * 8][tx] = (k < K && n < N) ? in[(size_t)k * N + n] : 0.f;
  }
  __syncthreads();
#pragma unroll
  for (int i = 0; i < 4; ++i) {
    const int n = n0 + ty + i * 8, kk = k0 + tx;
    out[(size_t)n * Kpad + kk] = __float2bfloat16(tile[tx][ty + i * 8]);
  }
}

// ---------------------------------------------------------------------------
// gate/up interleaved prep (coalesced)
// ---------------------------------------------------------------------------
__global__ __launch_bounds__(256) void gu_prep(
    const float* __restrict__ gate, const float* __restrict__ up,
    __hip_bfloat16* __restrict__ outw) {
  __shared__ float tile[32][33];
  const int l = blockIdx.z;
  const int c0 = blockIdx.x * 32, k0 = blockIdx.y * 32;
  const int tx = threadIdx.x & 31, ty = threadIdx.x >> 5;
#pragma unroll
  for (int role = 0; role < 2; ++role) {
    const float* src = (role ? up : gate) + (size_t)l * E_SZ * HID_SZ;
#pragma unroll
    for (int i = 0; i < 4; ++i) {
      const int k = k0 + ty + i * 8, c = c0 + tx;
      tile[ty + i * 8][tx] = (c < HID_SZ) ? src[(size_t)k * HID_SZ + c] : 0.f;
    }
    __syncthreads();
#pragma unroll
    for (int i = 0; i < 4; ++i) {
      const int c = c0 + ty + i * 8, kk = k0 + tx;
      const int n = ((c >> 4) << 5) | (role << 4) | (c & 15);
      outw[((size_t)l * 2816 + n) * E_SZ + kk] = __float2bfloat16(tile[tx][ty + i * 8]);
    }
    __syncthreads();
  }
}

// ---------------------------------------------------------------------------
// 64x64-tile GEMM with FUSED LN on A, 3-buffer counted-vmcnt pipeline.
// K = 512 always (NT = 8). EPI: 1 = bf16 out, 3 = SwiGLU->bf16.
// ---------------------------------------------------------------------------
template <int EPI>
__global__ __launch_bounds__(256) void gemm64ln(
    const float* __restrict__ X, const __hip_bfloat16* __restrict__ B,
    void* __restrict__ Cv, const float* __restrict__ stats,
    const float* __restrict__ gamma, const float* __restrict__ beta,
    int N, int K) {
  __shared__ char lds[49152];   // 3 buf x (A 8KB + B 8KB)
  __shared__ float gb[1024];
  const int tid = threadIdx.x, lane = tid & 63, w = tid >> 6;
  const int wr = w >> 1, wc = w & 1;
  const int m0 = blockIdx.y * 64, n0 = blockIdx.x * 64;
  const size_t SB = (size_t)K * 2;
  const char* Bb = (const char*)B + (size_t)n0 * SB;
  f32x4 acc[2][2] = {};
  const int lrow = lane >> 3;
  const int schunk = ((lane & 7) ^ lrow) * 16;
  const int kb = (lane >> 4) * 16;

  for (int i = tid; i < 512; i += 256) { gb[i] = gamma[i]; gb[512 + i] = beta[i]; }

  const int arow = tid >> 2, acol = (tid & 3) * 16;
  const int achunk0 = acol >> 3;
  const int akey = arow & 7;
  float mean, rstd;
  {
    const float* sp = stats + (size_t)(m0 + arow) * 32;
    float sum = 0.f, ssq = 0.f;
#pragma unroll
    for (int i = 0; i < 8; ++i) {
      float4 v = ((const float4*)sp)[i];
      sum += v.x + v.z; ssq += v.y + v.w;
    }
    mean = sum * (1.f / 512.f);
    const float var = ssq * (1.f / 512.f) - mean * mean;
    rstd = rsqrtf(var + 1e-5f);
  }
  const float* Xrow = X + (size_t)(m0 + arow) * K;
  __syncthreads();   // gb[] ready

  float xr[16];
  auto XLOAD = [&](int t) {
    const float* xs = Xrow + t * 64 + acol;
    *(float4*)&xr[0]  = ((const float4*)xs)[0];
    *(float4*)&xr[4]  = ((const float4*)xs)[1];
    *(float4*)&xr[8]  = ((const float4*)xs)[2];
    *(float4*)&xr[12] = ((const float4*)xs)[3];
  };
  auto STAGEB = [&](int buf, int t) {
    char* Bs = lds + buf * 16384 + 8192;
#pragma unroll
    for (int i = 0; i < 2; ++i) {
      const int row = w * 8 + 32 * i + lrow;
      const char* gbp = Bb + (size_t)row * SB + t * 128 + schunk;
      __builtin_amdgcn_global_load_lds(
          (const __attribute__((address_space(1))) unsigned int*)gbp,
          (__attribute__((address_space(3))) unsigned int*)(Bs + w * 1024 + i * 4096),
          16, 0, 0);
    }
  };
  auto WRITEA = [&](int buf, int t) {
    char* As = lds + buf * 16384;
    union { __hip_bfloat16 h[16]; int4 v[2]; } pk;
#pragma unroll
    for (int jj = 0; jj < 16; ++jj) {
      const int col = t * 64 + acol + jj;
      pk.h[jj] = __float2bfloat16((xr[jj] - mean) * rstd * gb[col] + gb[512 + col]);
    }
    *(int4*)(As + arow * 128 + (((achunk0 + 0) ^ akey) * 16)) = pk.v[0];
    *(int4*)(As + arow * 128 + (((achunk0 + 1) ^ akey) * 16)) = pk.v[1];
  };

  const int NT = 8;   // K = 512
  XLOAD(0); STAGEB(0, 0); WRITEA(0, 0);
  XLOAD(1); STAGEB(1, 1); WRITEA(1, 1);
  XLOAD(2);
#pragma unroll
  for (int t = 0; t < NT; ++t) {
    if (t + 2 < NT) { STAGEB((t + 2) % 3, t + 2); WRITEA((t + 2) % 3, t + 2); }
    if (t + 3 < NT) XLOAD(t + 3);
    if (t < NT - 1) asm volatile("s_waitcnt vmcnt(6) lgkmcnt(0)" ::: "memory");
    else            asm volatile("s_waitcnt vmcnt(0) lgkmcnt(0)" ::: "memory");
    __builtin_amdgcn_s_barrier();
    asm volatile("" ::: "memory");
    const char* As = lds + (t % 3) * 16384;
    const char* Bs = As + 8192;
    bf16x8 a[2][2], bb[2][2];
#pragma unroll
    for (int i = 0; i < 2; ++i) {
      const int ra = wr * 32 + i * 16 + (lane & 15);
      const int rb = wc * 32 + i * 16 + (lane & 15);
#pragma unroll
      for (int ks = 0; ks < 2; ++ks) {
        a[i][ks]  = *(const bf16x8*)(As + ra * 128 + ((ks * 64 + kb) ^ ((ra & 7) << 4)));
        bb[i][ks] = *(const bf16x8*)(Bs + rb * 128 + ((ks * 64 + kb) ^ ((rb & 7) << 4)));
      }
    }
    __builtin_amdgcn_s_setprio(1);
#pragma unroll
    for (int ks = 0; ks < 2; ++ks)
#pragma unroll
      for (int i = 0; i < 2; ++i)
#pragma unroll
        for (int j = 0; j < 2; ++j)
          acc[i][j] = __builtin_amdgcn_mfma_f32_16x16x32_bf16(a[i][ks], bb[j][ks], acc[i][j], 0, 0, 0);
    __builtin_amdgcn_s_setprio(0);
    asm volatile("" ::: "memory");
    __builtin_amdgcn_s_barrier();
    asm volatile("" ::: "memory");
  }

  const int cr = (lane >> 4) * 4, ccol = lane & 15;
  if (EPI == 3) {
    __hip_bfloat16* G = (__hip_bfloat16*)Cv;
    const int cg = (n0 >> 1) + wc * 16 + ccol;
#pragma unroll
    for (int i = 0; i < 2; ++i) {
#pragma unroll
      for (int rr = 0; rr < 4; ++rr) {
        const int m = m0 + wr * 32 + i * 16 + cr + rr;
        const float gv = acc[i][0][rr];
        const float uv = acc[i][1][rr];
        const float val = gv / (1.f + __expf(-gv)) * uv;
        G[(size_t)m * HID_PAD + cg] = __float2bfloat16(val);
      }
    }
  } else {
    __hip_bfloat16* O = (__hip_bfloat16*)Cv;
#pragma unroll
    for (int i = 0; i < 2; ++i)
#pragma unroll
      for (int j = 0; j < 2; ++j) {
        const int n = n0 + wc * 32 + j * 16 + ccol;
#pragma unroll
        for (int rr = 0; rr < 4; ++rr) {
          const int m = m0 + wr * 32 + i * 16 + cr + rr;
          O[(size_t)m * N + n] = __float2bfloat16(acc[i][j][rr]);
        }
      }
  }
}

// ---------------------------------------------------------------------------
// 64x64-tile GEMM + residual + LN-stats epilogue (proj/down). A,B bf16.
// 3-buffer pipeline with COUNTED vmcnt (unchanged from R16).
// ---------------------------------------------------------------------------
__global__ __launch_bounds__(256) void gemm64(
    const __hip_bfloat16* __restrict__ A, const __hip_bfloat16* __restrict__ B,
    float* __restrict__ C, const float* __restrict__ R,
    float* __restrict__ stats, int N, int K) {
  __shared__ char lds[49152];   // 3 buf x (A 8KB + B 8KB)
  const int tid = threadIdx.x, lane = tid & 63, w = tid >> 6;
  const int wr = w >> 1, wc = w & 1;
  const int m0 = blockIdx.y * 64, n0 = blockIdx.x * 64;
  const size_t SA = (size_t)K * 2;
  const char* Ab = (const char*)A + (size_t)m0 * SA;
  const char* Bb = (const char*)B + (size_t)n0 * SA;
  f32x4 acc[2][2] = {};
  const int lrow = lane >> 3;
  const int schunk = ((lane & 7) ^ lrow) * 16;
  const int kb = (lane >> 4) * 16;

  auto STAGE = [&](int buf, int t) {
    char* As = lds + buf * 16384;
    char* Bs = As + 8192;
    const int k0b = t * 128;   // 64 cols * 2B
#pragma unroll
    for (int i = 0; i < 2; ++i) {
      const int row = w * 8 + 32 * i + lrow;
      const char* ga = Ab + (size_t)row * SA + k0b + schunk;
      __builtin_amdgcn_global_load_lds(
          (const __attribute__((address_space(1))) unsigned int*)ga,
          (__attribute__((address_space(3))) unsigned int*)(As + w * 1024 + i * 4096),
          16, 0, 0);
      const char* gbp = Bb + (size_t)row * SA + k0b + schunk;
      __builtin_amdgcn_global_load_lds(
          (const __attribute__((address_space(1))) unsigned int*)gbp,
          (__attribute__((address_space(3))) unsigned int*)(Bs + w * 1024 + i * 4096),
          16, 0, 0);
    }
  };

  const int NT = K >> 6;   // 8 (proj) or 22 (down)
  STAGE(0, 0);
  if (NT > 1) STAGE(1, 1);
  for (int t = 0; t < NT; ++t) {
    if (t + 2 < NT) {
      STAGE((t + 2) % 3, t + 2);
      asm volatile("s_waitcnt vmcnt(8)" ::: "memory");
    } else if (t + 1 < NT) {
      asm volatile("s_waitcnt vmcnt(4)" ::: "memory");
    } else {
      asm volatile("s_waitcnt vmcnt(0)" ::: "memory");
    }
    __builtin_amdgcn_s_barrier();
    asm volatile("" ::: "memory");
    const char* As = lds + (t % 3) * 16384;
    const char* Bs = As + 8192;
    bf16x8 a[2][2], bb[2][2];
#pragma unroll
    for (int i = 0; i < 2; ++i) {
      const int ra = wr * 32 + i * 16 + (lane & 15);
      const int rb = wc * 32 + i * 16 + (lane & 15);
#pragma unroll
      for (int ks = 0; ks < 2; ++ks) {
        a[i][ks]  = *(const bf16x8*)(As + ra * 128 + ((ks * 64 + kb) ^ ((ra & 7) << 4)));
        bb[i][ks] = *(const bf16x8*)(Bs + rb * 128 + ((ks * 64 + kb) ^ ((rb & 7) << 4)));
      }
    }
    __builtin_amdgcn_s_setprio(1);
#pragma unroll
    for (int ks = 0; ks < 2; ++ks)
#pragma unroll
      for (int i = 0; i < 2; ++i)
#pragma unroll
        for (int j = 0; j < 2; ++j)
          acc[i][j] = __builtin_amdgcn_mfma_f32_16x16x32_bf16(a[i][ks], bb[j][ks], acc[i][j], 0, 0, 0);
    __builtin_amdgcn_s_setprio(0);
    asm volatile("" ::: "memory");
    __builtin_amdgcn_s_barrier();
    asm volatile("" ::: "memory");
  }

  const int cr = (lane >> 4) * 4, ccol = lane & 15;
  float vv[2][2][4];
#pragma unroll
  for (int i = 0; i < 2; ++i)
#pragma unroll
    for (int j = 0; j < 2; ++j) {
      const int n = n0 + wc * 32 + j * 16 + ccol;
#pragma unroll
      for (int rr = 0; rr < 4; ++rr) {
        const int m = m0 + wr * 32 + i * 16 + cr + rr;
        const float v = acc[i][j][rr] + R[(size_t)m * N + n];
        vv[i][j][rr] = v;
        C[(size_t)m * N + n] = v;
      }
    }
  const int slice = blockIdx.x * 2 + wc;
#pragma unroll
  for (int i = 0; i < 2; ++i) {
#pragma unroll
    for (int rr = 0; rr < 4; ++rr) {
      float s = vv[i][0][rr] + vv[i][1][rr];
      float q = vv[i][0][rr] * vv[i][0][rr] + vv[i][1][rr] * vv[i][1][rr];
#pragma unroll
      for (int o = 1; o < 16; o <<= 1) { s += __shfl_xor(s, o); q += __shfl_xor(q, o); }
      if ((lane & 15) == 0) {
        const int m = m0 + wr * 32 + i * 16 + cr + rr;
        float* st = stats + (size_t)m * 32 + slice * 2;
        st[0] = s; st[1] = q;
      }
    }
  }
}

// ---------------------------------------------------------------------------
// 256x128 HEAD GEMM: BK=32, 3 LDS buffers (72KB -> 2 blocks/CU), counted
// vmcnt(12/6/0), 32 MFMA per wave per iteration (2x arithmetic intensity).
// Swizzle key=row&3. XCD remap bx-major (8 by per bx share the B panel).
// ---------------------------------------------------------------------------
__global__ __launch_bounds__(256) void head_gemm(
    const __hip_bfloat16* __restrict__ A, const __hip_bfloat16* __restrict__ B,
    float* __restrict__ C, int N, int K) {
  __shared__ char lds[73728];   // 3 buf x (A 16KB + B 8KB)
  const int tid = threadIdx.x;
  const int lane = tid & 63, w = tid >> 6;
  const int wr = w >> 1, wc = w & 1;
  const int nwg = gridDim.x * gridDim.y;           // 393*8 = 3144
  const int id = blockIdx.y * gridDim.x + blockIdx.x;
  const int work = (id & 7) * (nwg >> 3) + (id >> 3);
  const int bx = work >> 3, by = work & 7;
  const int m0 = by * 256, n0 = bx * 128;
  const size_t SA = (size_t)K * 2;

  f32x4 acc[8][4] = {};
  const char* Ab = (const char*)A + (size_t)m0 * SA;
  const char* Bb = (const char*)B + (size_t)n0 * SA;

  const int srow = tid >> 2, schnk = tid & 3;

  auto STAGE = [&](int buf, int t) {
    char* As = lds + buf * 24576;
    char* Bs = As + 16384;
    const int k0b = t * 64;  // 32 cols * 2B
#pragma unroll
    for (int i = 0; i < 4; ++i) {          // A: rows 0..255
      const int r = srow + i * 64;
      const int gc = (schnk ^ (r & 3)) * 16;
      const char* ga = Ab + (size_t)r * SA + k0b + gc;
      __builtin_amdgcn_global_load_lds(
          (const __attribute__((address_space(1))) unsigned int*)ga,
          (__attribute__((address_space(3))) unsigned int*)(As + i * 4096 + tid * 16),
          16, 0, 0);
    }
#pragma unroll
    for (int i = 0; i < 2; ++i) {          // B: rows 0..127
      const int r = srow + i * 64;
      const int gc = (schnk ^ (r & 3)) * 16;
      const char* gbp = Bb + (size_t)r * SA + k0b + gc;
      __builtin_amdgcn_global_load_lds(
          (const __attribute__((address_space(1))) unsigned int*)gbp,
          (__attribute__((address_space(3))) unsigned int*)(Bs + i * 4096 + tid * 16),
          16, 0, 0);
    }
  };

  const int kb = lane >> 4;            // chunk index 0..3
  STAGE(0, 0);
  STAGE(1, 1);
#pragma unroll
  for (int t = 0; t < 16; ++t) {
    if (t + 2 < 16) STAGE((t + 2) % 3, t + 2);
    if (t <= 13)      asm volatile("s_waitcnt vmcnt(12)" ::: "memory");
    else if (t == 14) asm volatile("s_waitcnt vmcnt(6)" ::: "memory");
    else              asm volatile("s_waitcnt vmcnt(0)" ::: "memory");
    __builtin_amdgcn_s_barrier();
    asm volatile("" ::: "memory");
    const char* As = lds + (t % 3) * 24576;
    const char* Bs = As + 16384;
    bf16x8 a[8], b[4];
#pragma unroll
    for (int i = 0; i < 8; ++i) {
      const int ra = wr * 128 + i * 16 + (lane & 15);
      a[i] = *(const bf16x8*)(As + ra * 64 + ((kb ^ (ra & 3)) * 16));
    }
#pragma unroll
    for (int j = 0; j < 4; ++j) {
      const int rb = wc * 64 + j * 16 + (lane & 15);
      b[j] = *(const bf16x8*)(Bs + rb * 64 + ((kb ^ (rb & 3)) * 16));
    }
    __builtin_amdgcn_s_setprio(1);
#pragma unroll
    for (int i = 0; i < 8; ++i)
#pragma unroll
      for (int j = 0; j < 4; ++j)
        acc[i][j] = __builtin_amdgcn_mfma_f32_16x16x32_bf16(a[i], b[j], acc[i][j], 0, 0, 0);
    __builtin_amdgcn_s_setprio(0);
    asm volatile("" ::: "memory");
    __builtin_amdgcn_s_barrier();
    asm volatile("" ::: "memory");
  }

  const int cr = (lane >> 4) * 4, ccol = lane & 15;
#pragma unroll
  for (int i = 0; i < 8; ++i) {
#pragma unroll
    for (int j = 0; j < 4; ++j) {
      const int n = n0 + wc * 64 + j * 16 + ccol;
      if (n >= N) continue;
#pragma unroll
      for (int rr = 0; rr < 4; ++rr) {
        const int m = m0 + wr * 128 + i * 16 + cr + rr;
        C[(size_t)m * N + n] = acc[i][j][rr];
      }
    }
  }
}

// ---------------------------------------------------------------------------
// Flash attention (R14, unchanged): KV-parity split with 64-kv chunks.
// ---------------------------------------------------------------------------
__global__ __launch_bounds__(256, 1) void attn_mfma_kernel(
    const __hip_bfloat16* __restrict__ qkv, __hip_bfloat16* __restrict__ o) {
  const int bid = blockIdx.x;
  const int qb = bid & 15;
  const int h = (bid >> 4) & 7;
  const int b = bid >> 7;
  const int tid = threadIdx.x;
  const int w = tid >> 6, lane = tid & 63;
  const int g = w >> 1;
  const int wq = w & 1;
  const int l31 = lane & 31, hi = lane >> 5;
  const int q0w = qb * 64 + 32 * wq;
  const float slope = exp2f(-(float)(h + 1));
  const int rowstride = 3 * E_SZ;
  const int nch = qb + 1;
  const int niter = (nch + 1) >> 1;

  __shared__ char lds[32768];
  char* Kb = lds + g * 16384;
  char* Vb = Kb + 8192;

  bf16x8 qf[4];
  {
    const __hip_bfloat16* qrow = qkv + (size_t)(b * T_SZ + q0w + l31) * rowstride + h * HD_SZ;
#pragma unroll
    for (int dblk = 0; dblk < 4; ++dblk)
      qf[dblk] = *(const bf16x8*)(qrow + dblk * 16 + hi * 8);
  }

  f32x16 oacc[2][2] = {};
  float m[2] = {-INFINITY, -INFINITY}, lsum[2] = {0.f, 0.f};

  int4 kreg[4];
  int4 va[2], vb[2];
  const int ltid = tid & 127;
  const int jK = ltid >> 1, halfK = ltid & 1;
  const int jqV = ltid >> 2, qtV = ltid & 3;
  const int j0V = jqV * 2, d0V = qtV * 16;

  auto ISSUE = [&](int c) {
    const __hip_bfloat16* srcK = qkv + (size_t)(b * T_SZ + c * 64 + jK) * rowstride + E_SZ + h * HD_SZ + halfK * 32;
    kreg[0] = ((const int4*)srcK)[0]; kreg[1] = ((const int4*)srcK)[1];
    kreg[2] = ((const int4*)srcK)[2]; kreg[3] = ((const int4*)srcK)[3];
    const __hip_bfloat16* srcV = qkv + (size_t)(b * T_SZ + c * 64 + j0V) * rowstride + 2 * E_SZ + h * HD_SZ + d0V;
    va[0] = ((const int4*)srcV)[0]; va[1] = ((const int4*)srcV)[1];
    vb[0] = ((const int4*)(srcV + rowstride))[0]; vb[1] = ((const int4*)(srcV + rowstride))[1];
  };
  auto WRITE = [&]() {
#pragma unroll
    for (int u2 = 0; u2 < 4; ++u2) {
      const int d0 = halfK * 32 + u2 * 8;
      *(int4*)(Kb + jK * 128 + ((2 * d0) ^ ((jK & 7) << 4))) = kreg[u2];
    }
    union { int4 v[2]; unsigned short us[16]; } ua, ub;
    ua.v[0] = va[0]; ua.v[1] = va[1];
    ub.v[0] = vb[0]; ub.v[1] = vb[1];
#pragma unroll
    for (int e = 0; e < 16; ++e) {
      const int d = d0V + e;
      const unsigned wv = (unsigned)ua.us[e] | ((unsigned)ub.us[e] << 16);
      *(unsigned*)(Vb + d * 128 + ((2 * j0V) ^ ((d & 7) << 4))) = wv;
    }
  };

  if (g < nch) ISSUE(g);
  for (int it = 0; it < niter; ++it) {
    const int c = 2 * it + g;
    const bool act = c < nch;
    if (act) WRITE();
    __syncthreads();
    if (c + 2 < nch) ISSUE(c + 2);
    if (act) {
#pragma unroll
      for (int s = 0; s < 2; ++s) {
        const int j0 = c * 64 + 32 * s;
        if (j0 <= q0w + 31) {
          const int st = s;
          f32x16 sacc = {};
          const int jrow = 32 * s + l31;
          __builtin_amdgcn_s_setprio(1);
#pragma unroll
          for (int dblk = 0; dblk < 4; ++dblk) {
            bf16x8 kf = *(const bf16x8*)(Kb + jrow * 128 + ((dblk * 32 + hi * 16) ^ ((jrow & 7) << 4)));
            sacc = __builtin_amdgcn_mfma_f32_32x32x16_bf16(kf, qf[dblk], sacc, 0, 0, 0);
          }
          __builtin_amdgcn_s_setprio(0);
          const int qg = q0w + l31;
          float p[16];
          float tmax = -1e30f;
#pragma unroll
          for (int r = 0; r < 16; ++r) {
            const int jg = j0 + (r & 3) + 8 * (r >> 2) + 4 * hi;
            const float sv = (jg > qg) ? -1e9f : (sacc[r] * 0.125f + slope * (float)(qg - jg));
            p[r] = sv;
            tmax = fmaxf(tmax, sv);
          }
          tmax = fmaxf(tmax, __shfl_xor(tmax, 32));
          if (!__all(tmax <= m[st] + 8.f)) {
            const float mnew = fmaxf(m[st], tmax);
            const float corr = __expf(m[st] - mnew);
            lsum[st] *= corr;
#pragma unroll
            for (int dt = 0; dt < 2; ++dt)
#pragma unroll
              for (int r = 0; r < 16; ++r) oacc[st][dt][r] *= corr;
            m[st] = mnew;
          }
          float tsum = 0.f;
#pragma unroll
          for (int r = 0; r < 16; ++r) {
            p[r] = __expf(p[r] - m[st]);
            tsum += p[r];
          }
          tsum += __shfl_xor(tsum, 32);
          lsum[st] += tsum;
          unsigned wds[8];
#pragma unroll
          for (int k = 0; k < 8; ++k) {
            union { __hip_bfloat16 hh[2]; unsigned u; } pk_;
            pk_.hh[0] = __float2bfloat16(p[2 * k]);
            pk_.hh[1] = __float2bfloat16(p[2 * k + 1]);
            wds[k] = pk_.u;
          }
          bf16x8 pfrag[2];
#pragma unroll
          for (int jb = 0; jb < 2; ++jb) {
            const unsigned w0 = wds[4 * jb + 0], w1 = wds[4 * jb + 1];
            const unsigned w2 = wds[4 * jb + 2], w3 = wds[4 * jb + 3];
            const unsigned x2 = (unsigned)__shfl_xor((int)w2, 32);
            const unsigned x3 = (unsigned)__shfl_xor((int)w3, 32);
            const unsigned x0 = (unsigned)__shfl_xor((int)w0, 32);
            const unsigned x1 = (unsigned)__shfl_xor((int)w1, 32);
            union { unsigned u[4]; bf16x8 v; } pf;
            pf.u[0] = hi ? x2 : w0;
            pf.u[1] = hi ? x3 : w1;
            pf.u[2] = hi ? w2 : x0;
            pf.u[3] = hi ? w3 : x1;
            pfrag[jb] = pf.v;
          }
          __builtin_amdgcn_s_setprio(1);
#pragma unroll
          for (int dt = 0; dt < 2; ++dt) {
            const int row = dt * 32 + l31;
#pragma unroll
            for (int jb = 0; jb < 2; ++jb) {
              bf16x8 vt = *(const bf16x8*)(Vb + row * 128 + ((s * 64 + jb * 32 + hi * 16) ^ ((row & 7) << 4)));
              oacc[st][dt] = __builtin_amdgcn_mfma_f32_32x32x16_bf16(vt, pfrag[jb], oacc[st][dt], 0, 0, 0);
            }
          }
          __builtin_amdgcn_s_setprio(0);
        }
      }
    }
    __syncthreads();
  }

  float mW, lW;
  float Ow[2][16];
  if (g < nch) {
    const float mm = fmaxf(m[0], m[1]);
    const float a = __expf(m[0] - mm), b2 = __expf(m[1] - mm);
    mW = mm;
    lW = lsum[0] * a + lsum[1] * b2;
#pragma unroll
    for (int dt = 0; dt < 2; ++dt)
#pragma unroll
      for (int r = 0; r < 16; ++r)
        Ow[dt][r] = oacc[0][dt][r] * a + oacc[1][dt][r] * b2;
  } else {
    mW = -INFINITY; lW = 0.f;
#pragma unroll
    for (int dt = 0; dt < 2; ++dt)
#pragma unroll
      for (int r = 0; r < 16; ++r) Ow[dt][r] = 0.f;
  }

  float* Obuf = (float*)lds + wq * 2048;
  float* mlb  = (float*)lds + 4096 + wq * 64;
  __syncthreads();
  if (g == 1) {
#pragma unroll
    for (int dt = 0; dt < 2; ++dt)
#pragma unroll
      for (int r = 0; r < 16; ++r)
        Obuf[lane * 32 + dt * 16 + r] = Ow[dt][r];
    if (hi == 0) { mlb[l31 * 2] = mW; mlb[l31 * 2 + 1] = lW; }
  }
  __syncthreads();
  if (g == 0) {
    const float m1 = mlb[l31 * 2], l1 = mlb[l31 * 2 + 1];
    const float mmF = fmaxf(mW, m1);
    const float wA = __expf(mW - mmF), wB = __expf(m1 - mmF);
    const float inv = 1.f / (lW * wA + l1 * wB);
    __hip_bfloat16* orow = o + (size_t)(b * T_SZ + q0w + l31) * E_SZ + h * HD_SZ;
#pragma unroll
    for (int dt = 0; dt < 2; ++dt) {
#pragma unroll
      for (int gq = 0; gq < 4; ++gq) {
        union { __hip_bfloat16 hh[4]; short4 v; } ov;
#pragma unroll
        for (int e = 0; e < 4; ++e) {
          const int r = 4 * gq + e;
          const float o1 = Obuf[lane * 32 + dt * 16 + r];
          ov.hh[e] = __float2bfloat16((Ow[dt][r] * wA + o1 * wB) * inv);
        }
        *(short4*)(orow + dt * 32 + 4 * hi + 8 * gq) = ov.v;
      }
    }
  }
}

// ---------------------------------------------------------------------------
extern "C" void kernel_launch(void* const* d_in, const int* in_sizes, int n_in,
                              void* d_out, int out_size, void* d_ws, size_t ws_size,
                              hipStream_t stream) {
  const int* idx      = (const int*)d_in[0];
  const float* W_emb  = (const float*)d_in[1];
  const float* pos    = (const float*)d_in[2];
  const float* ln1_s  = (const float*)d_in[3];
  const float* ln1_b  = (const float*)d_in[4];
  const float* qkv_w  = (const float*)d_in[5];
  const float* proj_w = (const float*)d_in[6];
  const float* ln2_s  = (const float*)d_in[7];
  const float* ln2_b  = (const float*)d_in[8];
  const float* gate_w = (const float*)d_in[9];
  const float* up_w   = (const float*)d_in[10];
  const float* down_w = (const float*)d_in[11];
  const float* lnf_s  = (const float*)d_in[12];
  const float* lnf_b  = (const float*)d_in[13];
  float* out = (float*)d_out;

  char* p = (char*)d_ws;
  auto alloc = [&](size_t bytes) { char* q = p; p += (bytes + 255) & ~255ULL; return q; };
  float* x      = (float*)alloc((size_t)ROWS * E_SZ * 4);
  float* statsA = (float*)alloc((size_t)ROWS * 32 * 4);
  float* statsB = (float*)alloc((size_t)ROWS * 32 * 4);
  __hip_bfloat16* qkv_bf = (__hip_bfloat16*)alloc((size_t)ROWS * 3 * E_SZ * 2);
  __hip_bfloat16* h_bf  = (__hip_bfloat16*)alloc((size_t)ROWS * E_SZ * 2);
  __hip_bfloat16* o_bf  = (__hip_bfloat16*)alloc((size_t)ROWS * E_SZ * 2);
  __hip_bfloat16* g_bf  = (__hip_bfloat16*)alloc((size_t)ROWS * HID_PAD * 2);
  __hip_bfloat16* Wb    = (__hip_bfloat16*)alloc((size_t)V_PAD * E_SZ * 2);
  __hip_bfloat16* qkvwb = (__hip_bfloat16*)alloc((size_t)L_N * 3 * E_SZ * E_SZ * 2);
  __hip_bfloat16* projwb= (__hip_bfloat16*)alloc((size_t)L_N * E_SZ * E_SZ * 2);
  __hip_bfloat16* guwb  = (__hip_bfloat16*)alloc((size_t)L_N * 2816 * E_SZ * 2);
  __hip_bfloat16* downwb= (__hip_bfloat16*)alloc((size_t)L_N * E_SZ * HID_PAD * 2);

  // ---- weight prep ----
  convert_wemb<<<(V_PAD * E_SZ / 8 + 255) / 256, 256, 0, stream>>>(W_emb, Wb);
  transp_convert<<<dim3(3 * E_SZ / 32, E_SZ / 32, L_N), 256, 0, stream>>>(
      qkv_w, qkvwb, E_SZ, 3 * E_SZ, E_SZ, 3 * E_SZ);
  transp_convert<<<dim3(E_SZ / 32, E_SZ / 32, L_N), 256, 0, stream>>>(
      proj_w, projwb, E_SZ, E_SZ, E_SZ, E_SZ);
  gu_prep<<<dim3(HID_PAD / 32, E_SZ / 32, L_N), 256, 0, stream>>>(gate_w, up_w, guwb);
  transp_convert<<<dim3(E_SZ / 32, HID_PAD / 32, L_N), 256, 0, stream>>>(
      down_w, downwb, HID_SZ, E_SZ, HID_PAD, E_SZ);

  embed_kernel<<<ROWS, 128, 0, stream>>>(idx, W_emb, pos, x, statsA);

  for (int l = 0; l < L_N; ++l) {
    gemm64ln<1><<<dim3(3 * E_SZ / 64, ROWS / 64), 256, 0, stream>>>(
        x, qkvwb + (size_t)l * 3 * E_SZ * E_SZ, qkv_bf, statsA,
        ln1_s + l * E_SZ, ln1_b + l * E_SZ, 3 * E_SZ, E_SZ);
    attn_mfma_kernel<<<B_SZ * H_N * (T_SZ / 64), 256, 0, stream>>>(qkv_bf, o_bf);
    gemm64<<<dim3(E_SZ / 64, ROWS / 64), 256, 0, stream>>>(
        o_bf, projwb + (size_t)l * E_SZ * E_SZ, x, x, statsB, E_SZ, E_SZ);
    gemm64ln<3><<<dim3(2816 / 64, ROWS / 64), 256, 0, stream>>>(
        x, guwb + (size_t)l * 2816 * E_SZ, g_bf, statsB,
        ln2_s + l * E_SZ, ln2_b + l * E_SZ, 2816, E_SZ);
    gemm64<<<dim3(E_SZ / 64, ROWS / 64), 256, 0, stream>>>(
        g_bf, downwb + (size_t)l * E_SZ * HID_PAD, x, x, statsA, E_SZ, HID_PAD);
  }

  ln_from_stats<<<ROWS, 256, 0, stream>>>(x, statsA, lnf_s, lnf_b, h_bf);
  head_gemm<<<dim3(V_PAD / 128, ROWS / 256), 256, 0, stream>>>(h_bf, Wb, out, V_SZ, E_SZ);
}

// Round 19
// 1014.109 us; speedup vs baseline: 1.0133x; 1.0133x over previous
//
#include <hip/hip_runtime.h>
#include <hip/hip_bf16.h>
#include <math.h>

#define V_SZ 50257
#define V_PAD 50304
#define E_SZ 512
#define H_N 8
#define L_N 8
#define HID_SZ 1365
#define HID_PAD 1408
#define T_SZ 1024
#define B_SZ 2
#define HD_SZ 64
#define ROWS (B_SZ * T_SZ)   // 2048

typedef short bf16x8 __attribute__((ext_vector_type(8)));
typedef float f32x4 __attribute__((ext_vector_type(4)));
typedef float f32x16 __attribute__((ext_vector_type(16)));

// ---------------------------------------------------------------------------
// Embedding + LN-stats epilogue
// ---------------------------------------------------------------------------
__global__ __launch_bounds__(128) void embed_kernel(
    const int* __restrict__ idx, const float* __restrict__ W,
    const float* __restrict__ P, float* __restrict__ x,
    float* __restrict__ stats) {
  const int bt = blockIdx.x;
  const int t = bt & (T_SZ - 1);
  const int id = idx[bt];
  const int e = threadIdx.x * 4;
  float4 w = *(const float4*)(W + (size_t)id * E_SZ + e);
  float4 p = *(const float4*)(P + (size_t)t * E_SZ + e);
  float4 r;
  r.x = w.x + p.x; r.y = w.y + p.y; r.z = w.z + p.z; r.w = w.w + p.w;
  *(float4*)(x + (size_t)bt * E_SZ + e) = r;
  float s = r.x + r.y + r.z + r.w;
  float q = r.x * r.x + r.y * r.y + r.z * r.z + r.w * r.w;
#pragma unroll
  for (int o = 32; o; o >>= 1) { s += __shfl_xor(s, o); q += __shfl_xor(q, o); }
  __shared__ float sr[4];
  if ((threadIdx.x & 63) == 0) {
    sr[(threadIdx.x >> 6) * 2] = s;
    sr[(threadIdx.x >> 6) * 2 + 1] = q;
  }
  __syncthreads();
  if (threadIdx.x < 16) {
    float a = (threadIdx.x == 0) ? sr[0] + sr[2] : 0.f;
    float b2 = (threadIdx.x == 0) ? sr[1] + sr[3] : 0.f;
    float* st = stats + (size_t)bt * 32 + threadIdx.x * 2;
    st[0] = a; st[1] = b2;
  }
}

// ---------------------------------------------------------------------------
// LN from precomputed stats: h_bf = LN(x) (final LN before head)
// ---------------------------------------------------------------------------
__global__ __launch_bounds__(256) void ln_from_stats(
    const float* __restrict__ x, const float* __restrict__ stats,
    const float* __restrict__ gamma, const float* __restrict__ beta,
    __hip_bfloat16* __restrict__ out) {
  const int row = blockIdx.x;
  const int tid = threadIdx.x;
  const float* sp = stats + (size_t)row * 32;
  float sum = 0.f, ssq = 0.f;
#pragma unroll
  for (int i = 0; i < 8; ++i) {
    float4 v = ((const float4*)sp)[i];
    sum += v.x + v.z; ssq += v.y + v.w;
  }
  const float mean = sum * (1.f / 512.f);
  const float var = ssq * (1.f / 512.f) - mean * mean;
  const float rstd = rsqrtf(var + 1e-5f);
  const float2 v = *(const float2*)(x + (size_t)row * E_SZ + tid * 2);
  const float2 sv = *(const float2*)(gamma + tid * 2);
  const float2 bv = *(const float2*)(beta + tid * 2);
  __hip_bfloat162 ov;
  ov.x = __float2bfloat16((v.x - mean) * rstd * sv.x + bv.x);
  ov.y = __float2bfloat16((v.y - mean) * rstd * sv.y + bv.y);
  *(__hip_bfloat162*)(out + (size_t)row * E_SZ + tid * 2) = ov;
}

// ---------------------------------------------------------------------------
// W_emb f32 -> bf16 (padded rows)
// ---------------------------------------------------------------------------
__global__ __launch_bounds__(256) void convert_wemb(
    const float* __restrict__ W, __hip_bfloat16* __restrict__ Wb) {
  const int tid = blockIdx.x * 256 + threadIdx.x;
  const int row = tid >> 6;
  const int c = (tid & 63) * 8;
  union { __hip_bfloat16 h[8]; int4 v; } u;
  if (row < V_SZ) {
    const float* p = W + (size_t)row * E_SZ + c;
#pragma unroll
    for (int j = 0; j < 8; ++j) u.h[j] = __float2bfloat16(p[j]);
  } else {
#pragma unroll
    for (int j = 0; j < 8; ++j) u.h[j] = __float2bfloat16(0.f);
  }
  *(int4*)(Wb + (size_t)row * E_SZ + c) = u.v;
}

// ---------------------------------------------------------------------------
// Batched transpose+convert [L][K][N] f32 -> [L][Npad][Kpad] bf16
// ---------------------------------------------------------------------------
__global__ __launch_bounds__(256) void transp_convert(
    const float* __restrict__ in, __hip_bfloat16* __restrict__ out,
    int K, int N, int Kpad, int Npad) {
  __shared__ float tile[32][33];
  const int l = blockIdx.z;
  in  += (size_t)l * K * N;
  out += (size_t)l * Npad * Kpad;
  const int tx = threadIdx.x & 31, ty = threadIdx.x >> 5;
  const int n0 = blockIdx.x * 32, k0 = blockIdx.y * 32;
#pragma unroll
  for (int i = 0; i < 4; ++i) {
    const int k = k0 + ty + i * 8, n = n0 + tx;
    tile[ty + i * 8][tx] = (k < K && n < N) ? in[(size_t)k * N + n] : 0.f;
  }
  __syncthreads();
#pragma unroll
  for (int i = 0; i < 4; ++i) {
    const int n = n0 + ty + i * 8, kk = k0 + tx;
    out[(size_t)n * Kpad + kk] = __float2bfloat16(tile[tx][ty + i * 8]);
  }
}

// ---------------------------------------------------------------------------
// gate/up interleaved prep (coalesced)
// ---------------------------------------------------------------------------
__global__ __launch_bounds__(256) void gu_prep(
    const float* __restrict__ gate, const float* __restrict__ up,
    __hip_bfloat16* __restrict__ outw) {
  __shared__ float tile[32][33];
  const int l = blockIdx.z;
  const int c0 = blockIdx.x * 32, k0 = blockIdx.y * 32;
  const int tx = threadIdx.x & 31, ty = threadIdx.x >> 5;
#pragma unroll
  for (int role = 0; role < 2; ++role) {
    const float* src = (role ? up : gate) + (size_t)l * E_SZ * HID_SZ;
#pragma unroll
    for (int i = 0; i < 4; ++i) {
      const int k = k0 + ty + i * 8, c = c0 + tx;
      tile[ty + i * 8][tx] = (c < HID_SZ) ? src[(size_t)k * HID_SZ + c] : 0.f;
    }
    __syncthreads();
#pragma unroll
    for (int i = 0; i < 4; ++i) {
      const int c = c0 + ty + i * 8, kk = k0 + tx;
      const int n = ((c >> 4) << 5) | (role << 4) | (c & 15);
      outw[((size_t)l * 2816 + n) * E_SZ + kk] = __float2bfloat16(tile[tx][ty + i * 8]);
    }
    __syncthreads();
  }
}

// ---------------------------------------------------------------------------
// 64x64-tile GEMM with FUSED LN on A, 3-buffer counted-vmcnt pipeline.
// K = 512 always (NT = 8). EPI: 1 = bf16 out, 3 = SwiGLU->bf16.
// ---------------------------------------------------------------------------
template <int EPI>
__global__ __launch_bounds__(256) void gemm64ln(
    const float* __restrict__ X, const __hip_bfloat16* __restrict__ B,
    void* __restrict__ Cv, const float* __restrict__ stats,
    const float* __restrict__ gamma, const float* __restrict__ beta,
    int N, int K) {
  __shared__ char lds[49152];   // 3 buf x (A 8KB + B 8KB)
  __shared__ float gb[1024];
  const int tid = threadIdx.x, lane = tid & 63, w = tid >> 6;
  const int wr = w >> 1, wc = w & 1;
  const int m0 = blockIdx.y * 64, n0 = blockIdx.x * 64;
  const size_t SB = (size_t)K * 2;
  const char* Bb = (const char*)B + (size_t)n0 * SB;
  f32x4 acc[2][2] = {};
  const int lrow = lane >> 3;
  const int schunk = ((lane & 7) ^ lrow) * 16;
  const int kb = (lane >> 4) * 16;

  for (int i = tid; i < 512; i += 256) { gb[i] = gamma[i]; gb[512 + i] = beta[i]; }

  const int arow = tid >> 2, acol = (tid & 3) * 16;
  const int achunk0 = acol >> 3;
  const int akey = arow & 7;
  float mean, rstd;
  {
    const float* sp = stats + (size_t)(m0 + arow) * 32;
    float sum = 0.f, ssq = 0.f;
#pragma unroll
    for (int i = 0; i < 8; ++i) {
      float4 v = ((const float4*)sp)[i];
      sum += v.x + v.z; ssq += v.y + v.w;
    }
    mean = sum * (1.f / 512.f);
    const float var = ssq * (1.f / 512.f) - mean * mean;
    rstd = rsqrtf(var + 1e-5f);
  }
  const float* Xrow = X + (size_t)(m0 + arow) * K;
  __syncthreads();   // gb[] ready

  float xr[16];
  auto XLOAD = [&](int t) {
    const float* xs = Xrow + t * 64 + acol;
    *(float4*)&xr[0]  = ((const float4*)xs)[0];
    *(float4*)&xr[4]  = ((const float4*)xs)[1];
    *(float4*)&xr[8]  = ((const float4*)xs)[2];
    *(float4*)&xr[12] = ((const float4*)xs)[3];
  };
  auto STAGEB = [&](int buf, int t) {
    char* Bs = lds + buf * 16384 + 8192;
#pragma unroll
    for (int i = 0; i < 2; ++i) {
      const int row = w * 8 + 32 * i + lrow;
      const char* gbp = Bb + (size_t)row * SB + t * 128 + schunk;
      __builtin_amdgcn_global_load_lds(
          (const __attribute__((address_space(1))) unsigned int*)gbp,
          (__attribute__((address_space(3))) unsigned int*)(Bs + w * 1024 + i * 4096),
          16, 0, 0);
    }
  };
  auto WRITEA = [&](int buf, int t) {
    char* As = lds + buf * 16384;
    union { __hip_bfloat16 h[16]; int4 v[2]; } pk;
#pragma unroll
    for (int jj = 0; jj < 16; ++jj) {
      const int col = t * 64 + acol + jj;
      pk.h[jj] = __float2bfloat16((xr[jj] - mean) * rstd * gb[col] + gb[512 + col]);
    }
    *(int4*)(As + arow * 128 + (((achunk0 + 0) ^ akey) * 16)) = pk.v[0];
    *(int4*)(As + arow * 128 + (((achunk0 + 1) ^ akey) * 16)) = pk.v[1];
  };

  const int NT = 8;   // K = 512
  XLOAD(0); STAGEB(0, 0); WRITEA(0, 0);
  XLOAD(1); STAGEB(1, 1); WRITEA(1, 1);
  XLOAD(2);
#pragma unroll
  for (int t = 0; t < NT; ++t) {
    if (t + 2 < NT) { STAGEB((t + 2) % 3, t + 2); WRITEA((t + 2) % 3, t + 2); }
    if (t + 3 < NT) XLOAD(t + 3);
    if (t < NT - 1) asm volatile("s_waitcnt vmcnt(6) lgkmcnt(0)" ::: "memory");
    else            asm volatile("s_waitcnt vmcnt(0) lgkmcnt(0)" ::: "memory");
    __builtin_amdgcn_s_barrier();
    asm volatile("" ::: "memory");
    const char* As = lds + (t % 3) * 16384;
    const char* Bs = As + 8192;
    bf16x8 a[2][2], bb[2][2];
#pragma unroll
    for (int i = 0; i < 2; ++i) {
      const int ra = wr * 32 + i * 16 + (lane & 15);
      const int rb = wc * 32 + i * 16 + (lane & 15);
#pragma unroll
      for (int ks = 0; ks < 2; ++ks) {
        a[i][ks]  = *(const bf16x8*)(As + ra * 128 + ((ks * 64 + kb) ^ ((ra & 7) << 4)));
        bb[i][ks] = *(const bf16x8*)(Bs + rb * 128 + ((ks * 64 + kb) ^ ((rb & 7) << 4)));
      }
    }
    __builtin_amdgcn_s_setprio(1);
#pragma unroll
    for (int ks = 0; ks < 2; ++ks)
#pragma unroll
      for (int i = 0; i < 2; ++i)
#pragma unroll
        for (int j = 0; j < 2; ++j)
          acc[i][j] = __builtin_amdgcn_mfma_f32_16x16x32_bf16(a[i][ks], bb[j][ks], acc[i][j], 0, 0, 0);
    __builtin_amdgcn_s_setprio(0);
    asm volatile("" ::: "memory");
    __builtin_amdgcn_s_barrier();
    asm volatile("" ::: "memory");
  }

  const int cr = (lane >> 4) * 4, ccol = lane & 15;
  if (EPI == 3) {
    __hip_bfloat16* G = (__hip_bfloat16*)Cv;
    const int cg = (n0 >> 1) + wc * 16 + ccol;
#pragma unroll
    for (int i = 0; i < 2; ++i) {
#pragma unroll
      for (int rr = 0; rr < 4; ++rr) {
        const int m = m0 + wr * 32 + i * 16 + cr + rr;
        const float gv = acc[i][0][rr];
        const float uv = acc[i][1][rr];
        const float val = gv / (1.f + __expf(-gv)) * uv;
        G[(size_t)m * HID_PAD + cg] = __float2bfloat16(val);
      }
    }
  } else {
    __hip_bfloat16* O = (__hip_bfloat16*)Cv;
#pragma unroll
    for (int i = 0; i < 2; ++i)
#pragma unroll
      for (int j = 0; j < 2; ++j) {
        const int n = n0 + wc * 32 + j * 16 + ccol;
#pragma unroll
        for (int rr = 0; rr < 4; ++rr) {
          const int m = m0 + wr * 32 + i * 16 + cr + rr;
          O[(size_t)m * N + n] = __float2bfloat16(acc[i][j][rr]);
        }
      }
  }
}

// ---------------------------------------------------------------------------
// 64x64-tile GEMM + residual + LN-stats epilogue (proj/down). A,B bf16.
// 3-buffer pipeline with COUNTED vmcnt.
// ---------------------------------------------------------------------------
__global__ __launch_bounds__(256) void gemm64(
    const __hip_bfloat16* __restrict__ A, const __hip_bfloat16* __restrict__ B,
    float* __restrict__ C, const float* __restrict__ R,
    float* __restrict__ stats, int N, int K) {
  __shared__ char lds[49152];   // 3 buf x (A 8KB + B 8KB)
  const int tid = threadIdx.x, lane = tid & 63, w = tid >> 6;
  const int wr = w >> 1, wc = w & 1;
  const int m0 = blockIdx.y * 64, n0 = blockIdx.x * 64;
  const size_t SA = (size_t)K * 2;
  const char* Ab = (const char*)A + (size_t)m0 * SA;
  const char* Bb = (const char*)B + (size_t)n0 * SA;
  f32x4 acc[2][2] = {};
  const int lrow = lane >> 3;
  const int schunk = ((lane & 7) ^ lrow) * 16;
  const int kb = (lane >> 4) * 16;

  auto STAGE = [&](int buf, int t) {
    char* As = lds + buf * 16384;
    char* Bs = As + 8192;
    const int k0b = t * 128;   // 64 cols * 2B
#pragma unroll
    for (int i = 0; i < 2; ++i) {
      const int row = w * 8 + 32 * i + lrow;
      const char* ga = Ab + (size_t)row * SA + k0b + schunk;
      __builtin_amdgcn_global_load_lds(
          (const __attribute__((address_space(1))) unsigned int*)ga,
          (__attribute__((address_space(3))) unsigned int*)(As + w * 1024 + i * 4096),
          16, 0, 0);
      const char* gbp = Bb + (size_t)row * SA + k0b + schunk;
      __builtin_amdgcn_global_load_lds(
          (const __attribute__((address_space(1))) unsigned int*)gbp,
          (__attribute__((address_space(3))) unsigned int*)(Bs + w * 1024 + i * 4096),
          16, 0, 0);
    }
  };

  const int NT = K >> 6;   // 8 (proj) or 22 (down)
  STAGE(0, 0);
  if (NT > 1) STAGE(1, 1);
  for (int t = 0; t < NT; ++t) {
    if (t + 2 < NT) {
      STAGE((t + 2) % 3, t + 2);
      asm volatile("s_waitcnt vmcnt(8)" ::: "memory");
    } else if (t + 1 < NT) {
      asm volatile("s_waitcnt vmcnt(4)" ::: "memory");
    } else {
      asm volatile("s_waitcnt vmcnt(0)" ::: "memory");
    }
    __builtin_amdgcn_s_barrier();
    asm volatile("" ::: "memory");
    const char* As = lds + (t % 3) * 16384;
    const char* Bs = As + 8192;
    bf16x8 a[2][2], bb[2][2];
#pragma unroll
    for (int i = 0; i < 2; ++i) {
      const int ra = wr * 32 + i * 16 + (lane & 15);
      const int rb = wc * 32 + i * 16 + (lane & 15);
#pragma unroll
      for (int ks = 0; ks < 2; ++ks) {
        a[i][ks]  = *(const bf16x8*)(As + ra * 128 + ((ks * 64 + kb) ^ ((ra & 7) << 4)));
        bb[i][ks] = *(const bf16x8*)(Bs + rb * 128 + ((ks * 64 + kb) ^ ((rb & 7) << 4)));
      }
    }
    __builtin_amdgcn_s_setprio(1);
#pragma unroll
    for (int ks = 0; ks < 2; ++ks)
#pragma unroll
      for (int i = 0; i < 2; ++i)
#pragma unroll
        for (int j = 0; j < 2; ++j)
          acc[i][j] = __builtin_amdgcn_mfma_f32_16x16x32_bf16(a[i][ks], bb[j][ks], acc[i][j], 0, 0, 0);
    __builtin_amdgcn_s_setprio(0);
    asm volatile("" ::: "memory");
    __builtin_amdgcn_s_barrier();
    asm volatile("" ::: "memory");
  }

  const int cr = (lane >> 4) * 4, ccol = lane & 15;
  float vv[2][2][4];
#pragma unroll
  for (int i = 0; i < 2; ++i)
#pragma unroll
    for (int j = 0; j < 2; ++j) {
      const int n = n0 + wc * 32 + j * 16 + ccol;
#pragma unroll
      for (int rr = 0; rr < 4; ++rr) {
        const int m = m0 + wr * 32 + i * 16 + cr + rr;
        const float v = acc[i][j][rr] + R[(size_t)m * N + n];
        vv[i][j][rr] = v;
        C[(size_t)m * N + n] = v;
      }
    }
  const int slice = blockIdx.x * 2 + wc;
#pragma unroll
  for (int i = 0; i < 2; ++i) {
#pragma unroll
    for (int rr = 0; rr < 4; ++rr) {
      float s = vv[i][0][rr] + vv[i][1][rr];
      float q = vv[i][0][rr] * vv[i][0][rr] + vv[i][1][rr] * vv[i][1][rr];
#pragma unroll
      for (int o = 1; o < 16; o <<= 1) { s += __shfl_xor(s, o); q += __shfl_xor(q, o); }
      if ((lane & 15) == 0) {
        const int m = m0 + wr * 32 + i * 16 + cr + rr;
        float* st = stats + (size_t)m * 32 + slice * 2;
        st[0] = s; st[1] = q;
      }
    }
  }
}

// ---------------------------------------------------------------------------
// 128x128 HEAD GEMM (R13/R17 config): BK=32, 3 LDS buffers, counted vmcnt,
// swizzle key=row&3, XCD bx-major remap, direct stores.
// ---------------------------------------------------------------------------
__global__ __launch_bounds__(256) void head_gemm(
    const __hip_bfloat16* __restrict__ A, const __hip_bfloat16* __restrict__ B,
    float* __restrict__ C, int N, int K) {
  __shared__ char lds[49152];   // 3 buf x (A 8KB + B 8KB)
  const int tid = threadIdx.x;
  const int lane = tid & 63, w = tid >> 6;
  const int wr = w >> 1, wc = w & 1;
  const int nwg = gridDim.x * gridDim.y;
  const int id = blockIdx.y * gridDim.x + blockIdx.x;
  const int work = (id & 7) * (nwg >> 3) + (id >> 3);
  const int bx = work >> 4, by = work & 15;
  const int m0 = by * 128, n0 = bx * 128;
  const size_t SA = (size_t)K * 2;

  f32x4 acc[4][4] = {};
  const char* Ab = (const char*)A + (size_t)m0 * SA;
  const char* Bb = (const char*)B + (size_t)n0 * SA;

  const int srow = tid >> 2, schnk = tid & 3;

  auto STAGE = [&](int buf, int t) {
    char* As = lds + buf * 16384;
    char* Bs = As + 8192;
    const int k0b = t * 64;  // 32 cols * 2B
#pragma unroll
    for (int i = 0; i < 2; ++i) {
      const int r = srow + i * 64;
      const int gc = (schnk ^ (r & 3)) * 16;
      const char* ga = Ab + (size_t)r * SA + k0b + gc;
      __builtin_amdgcn_global_load_lds(
          (const __attribute__((address_space(1))) unsigned int*)ga,
          (__attribute__((address_space(3))) unsigned int*)(As + i * 4096 + tid * 16),
          16, 0, 0);
      const char* gbp = Bb + (size_t)r * SA + k0b + gc;
      __builtin_amdgcn_global_load_lds(
          (const __attribute__((address_space(1))) unsigned int*)gbp,
          (__attribute__((address_space(3))) unsigned int*)(Bs + i * 4096 + tid * 16),
          16, 0, 0);
    }
  };

  const int kb = lane >> 4;            // chunk index 0..3
  STAGE(0, 0);
  STAGE(1, 1);
#pragma unroll
  for (int t = 0; t < 16; ++t) {
    if (t + 2 < 16) STAGE((t + 2) % 3, t + 2);
    if (t <= 13)      asm volatile("s_waitcnt vmcnt(8)" ::: "memory");
    else if (t == 14) asm volatile("s_waitcnt vmcnt(4)" ::: "memory");
    else              asm volatile("s_waitcnt vmcnt(0)" ::: "memory");
    __builtin_amdgcn_s_barrier();
    asm volatile("" ::: "memory");
    const char* As = lds + (t % 3) * 16384;
    const char* Bs = As + 8192;
    bf16x8 a[4], b[4];
#pragma unroll
    for (int i = 0; i < 4; ++i) {
      const int ra = wr * 64 + i * 16 + (lane & 15);
      const int rb = wc * 64 + i * 16 + (lane & 15);
      a[i] = *(const bf16x8*)(As + ra * 64 + ((kb ^ (ra & 3)) * 16));
      b[i] = *(const bf16x8*)(Bs + rb * 64 + ((kb ^ (rb & 3)) * 16));
    }
    __builtin_amdgcn_s_setprio(1);
#pragma unroll
    for (int i = 0; i < 4; ++i)
#pragma unroll
      for (int j = 0; j < 4; ++j)
        acc[i][j] = __builtin_amdgcn_mfma_f32_16x16x32_bf16(a[i], b[j], acc[i][j], 0, 0, 0);
    __builtin_amdgcn_s_setprio(0);
    asm volatile("" ::: "memory");
    __builtin_amdgcn_s_barrier();
    asm volatile("" ::: "memory");
  }

  const int cr = (lane >> 4) * 4, ccol = lane & 15;
#pragma unroll
  for (int i = 0; i < 4; ++i) {
#pragma unroll
    for (int j = 0; j < 4; ++j) {
      const int n = n0 + wc * 64 + j * 16 + ccol;
      if (n >= N) continue;
#pragma unroll
      for (int rr = 0; rr < 4; ++rr) {
        const int m = m0 + wr * 64 + i * 16 + cr + rr;
        C[(size_t)m * N + n] = acc[i][j][rr];
      }
    }
  }
}

// ---------------------------------------------------------------------------
// Flash attention (R14): KV-parity split with 64-kv chunks per group.
// ---------------------------------------------------------------------------
__global__ __launch_bounds__(256, 1) void attn_mfma_kernel(
    const __hip_bfloat16* __restrict__ qkv, __hip_bfloat16* __restrict__ o) {
  const int bid = blockIdx.x;
  const int qb = bid & 15;
  const int h = (bid >> 4) & 7;
  const int b = bid >> 7;
  const int tid = threadIdx.x;
  const int w = tid >> 6, lane = tid & 63;
  const int g = w >> 1;
  const int wq = w & 1;
  const int l31 = lane & 31, hi = lane >> 5;
  const int q0w = qb * 64 + 32 * wq;
  const float slope = exp2f(-(float)(h + 1));
  const int rowstride = 3 * E_SZ;
  const int nch = qb + 1;
  const int niter = (nch + 1) >> 1;

  __shared__ char lds[32768];
  char* Kb = lds + g * 16384;
  char* Vb = Kb + 8192;

  bf16x8 qf[4];
  {
    const __hip_bfloat16* qrow = qkv + (size_t)(b * T_SZ + q0w + l31) * rowstride + h * HD_SZ;
#pragma unroll
    for (int dblk = 0; dblk < 4; ++dblk)
      qf[dblk] = *(const bf16x8*)(qrow + dblk * 16 + hi * 8);
  }

  f32x16 oacc[2][2] = {};
  float m[2] = {-INFINITY, -INFINITY}, lsum[2] = {0.f, 0.f};

  int4 kreg[4];
  int4 va[2], vb[2];
  const int ltid = tid & 127;
  const int jK = ltid >> 1, halfK = ltid & 1;
  const int jqV = ltid >> 2, qtV = ltid & 3;
  const int j0V = jqV * 2, d0V = qtV * 16;

  auto ISSUE = [&](int c) {
    const __hip_bfloat16* srcK = qkv + (size_t)(b * T_SZ + c * 64 + jK) * rowstride + E_SZ + h * HD_SZ + halfK * 32;
    kreg[0] = ((const int4*)srcK)[0]; kreg[1] = ((const int4*)srcK)[1];
    kreg[2] = ((const int4*)srcK)[2]; kreg[3] = ((const int4*)srcK)[3];
    const __hip_bfloat16* srcV = qkv + (size_t)(b * T_SZ + c * 64 + j0V) * rowstride + 2 * E_SZ + h * HD_SZ + d0V;
    va[0] = ((const int4*)srcV)[0]; va[1] = ((const int4*)srcV)[1];
    vb[0] = ((const int4*)(srcV + rowstride))[0]; vb[1] = ((const int4*)(srcV + rowstride))[1];
  };
  auto WRITE = [&]() {
#pragma unroll
    for (int u2 = 0; u2 < 4; ++u2) {
      const int d0 = halfK * 32 + u2 * 8;
      *(int4*)(Kb + jK * 128 + ((2 * d0) ^ ((jK & 7) << 4))) = kreg[u2];
    }
    union { int4 v[2]; unsigned short us[16]; } ua, ub;
    ua.v[0] = va[0]; ua.v[1] = va[1];
    ub.v[0] = vb[0]; ub.v[1] = vb[1];
#pragma unroll
    for (int e = 0; e < 16; ++e) {
      const int d = d0V + e;
      const unsigned wv = (unsigned)ua.us[e] | ((unsigned)ub.us[e] << 16);
      *(unsigned*)(Vb + d * 128 + ((2 * j0V) ^ ((d & 7) << 4))) = wv;
    }
  };

  if (g < nch) ISSUE(g);
  for (int it = 0; it < niter; ++it) {
    const int c = 2 * it + g;
    const bool act = c < nch;
    if (act) WRITE();
    __syncthreads();
    if (c + 2 < nch) ISSUE(c + 2);
    if (act) {
#pragma unroll
      for (int s = 0; s < 2; ++s) {
        const int j0 = c * 64 + 32 * s;
        if (j0 <= q0w + 31) {
          const int st = s;
          f32x16 sacc = {};
          const int jrow = 32 * s + l31;
          __builtin_amdgcn_s_setprio(1);
#pragma unroll
          for (int dblk = 0; dblk < 4; ++dblk) {
            bf16x8 kf = *(const bf16x8*)(Kb + jrow * 128 + ((dblk * 32 + hi * 16) ^ ((jrow & 7) << 4)));
            sacc = __builtin_amdgcn_mfma_f32_32x32x16_bf16(kf, qf[dblk], sacc, 0, 0, 0);
          }
          __builtin_amdgcn_s_setprio(0);
          const int qg = q0w + l31;
          float p[16];
          float tmax = -1e30f;
#pragma unroll
          for (int r = 0; r < 16; ++r) {
            const int jg = j0 + (r & 3) + 8 * (r >> 2) + 4 * hi;
            const float sv = (jg > qg) ? -1e9f : (sacc[r] * 0.125f + slope * (float)(qg - jg));
            p[r] = sv;
            tmax = fmaxf(tmax, sv);
          }
          tmax = fmaxf(tmax, __shfl_xor(tmax, 32));
          if (!__all(tmax <= m[st] + 8.f)) {
            const float mnew = fmaxf(m[st], tmax);
            const float corr = __expf(m[st] - mnew);
            lsum[st] *= corr;
#pragma unroll
            for (int dt = 0; dt < 2; ++dt)
#pragma unroll
              for (int r = 0; r < 16; ++r) oacc[st][dt][r] *= corr;
            m[st] = mnew;
          }
          float tsum = 0.f;
#pragma unroll
          for (int r = 0; r < 16; ++r) {
            p[r] = __expf(p[r] - m[st]);
            tsum += p[r];
          }
          tsum += __shfl_xor(tsum, 32);
          lsum[st] += tsum;
          unsigned wds[8];
#pragma unroll
          for (int k = 0; k < 8; ++k) {
            union { __hip_bfloat16 hh[2]; unsigned u; } pk_;
            pk_.hh[0] = __float2bfloat16(p[2 * k]);
            pk_.hh[1] = __float2bfloat16(p[2 * k + 1]);
            wds[k] = pk_.u;
          }
          bf16x8 pfrag[2];
#pragma unroll
          for (int jb = 0; jb < 2; ++jb) {
            const unsigned w0 = wds[4 * jb + 0], w1 = wds[4 * jb + 1];
            const unsigned w2 = wds[4 * jb + 2], w3 = wds[4 * jb + 3];
            const unsigned x2 = (unsigned)__shfl_xor((int)w2, 32);
            const unsigned x3 = (unsigned)__shfl_xor((int)w3, 32);
            const unsigned x0 = (unsigned)__shfl_xor((int)w0, 32);
            const unsigned x1 = (unsigned)__shfl_xor((int)w1, 32);
            union { unsigned u[4]; bf16x8 v; } pf;
            pf.u[0] = hi ? x2 : w0;
            pf.u[1] = hi ? x3 : w1;
            pf.u[2] = hi ? w2 : x0;
            pf.u[3] = hi ? w3 : x1;
            pfrag[jb] = pf.v;
          }
          __builtin_amdgcn_s_setprio(1);
#pragma unroll
          for (int dt = 0; dt < 2; ++dt) {
            const int row = dt * 32 + l31;
#pragma unroll
            for (int jb = 0; jb < 2; ++jb) {
              bf16x8 vt = *(const bf16x8*)(Vb + row * 128 + ((s * 64 + jb * 32 + hi * 16) ^ ((row & 7) << 4)));
              oacc[st][dt] = __builtin_amdgcn_mfma_f32_32x32x16_bf16(vt, pfrag[jb], oacc[st][dt], 0, 0, 0);
            }
          }
          __builtin_amdgcn_s_setprio(0);
        }
      }
    }
    __syncthreads();
  }

  float mW, lW;
  float Ow[2][16];
  if (g < nch) {
    const float mm = fmaxf(m[0], m[1]);
    const float a = __expf(m[0] - mm), b2 = __expf(m[1] - mm);
    mW = mm;
    lW = lsum[0] * a + lsum[1] * b2;
#pragma unroll
    for (int dt = 0; dt < 2; ++dt)
#pragma unroll
      for (int r = 0; r < 16; ++r)
        Ow[dt][r] = oacc[0][dt][r] * a + oacc[1][dt][r] * b2;
  } else {
    mW = -INFINITY; lW = 0.f;
#pragma unroll
    for (int dt = 0; dt < 2; ++dt)
#pragma unroll
      for (int r = 0; r < 16; ++r) Ow[dt][r] = 0.f;
  }

  float* Obuf = (float*)lds + wq * 2048;
  float* mlb  = (float*)lds + 4096 + wq * 64;
  __syncthreads();
  if (g == 1) {
#pragma unroll
    for (int dt = 0; dt < 2; ++dt)
#pragma unroll
      for (int r = 0; r < 16; ++r)
        Obuf[lane * 32 + dt * 16 + r] = Ow[dt][r];
    if (hi == 0) { mlb[l31 * 2] = mW; mlb[l31 * 2 + 1] = lW; }
  }
  __syncthreads();
  if (g == 0) {
    const float m1 = mlb[l31 * 2], l1 = mlb[l31 * 2 + 1];
    const float mmF = fmaxf(mW, m1);
    const float wA = __expf(mW - mmF), wB = __expf(m1 - mmF);
    const float inv = 1.f / (lW * wA + l1 * wB);
    __hip_bfloat16* orow = o + (size_t)(b * T_SZ + q0w + l31) * E_SZ + h * HD_SZ;
#pragma unroll
    for (int dt = 0; dt < 2; ++dt) {
#pragma unroll
      for (int gq = 0; gq < 4; ++gq) {
        union { __hip_bfloat16 hh[4]; short4 v; } ov;
#pragma unroll
        for (int e = 0; e < 4; ++e) {
          const int r = 4 * gq + e;
          const float o1 = Obuf[lane * 32 + dt * 16 + r];
          ov.hh[e] = __float2bfloat16((Ow[dt][r] * wA + o1 * wB) * inv);
        }
        *(short4*)(orow + dt * 32 + 4 * hi + 8 * gq) = ov.v;
      }
    }
  }
}

// ---------------------------------------------------------------------------
extern "C" void kernel_launch(void* const* d_in, const int* in_sizes, int n_in,
                              void* d_out, int out_size, void* d_ws, size_t ws_size,
                              hipStream_t stream) {
  const int* idx      = (const int*)d_in[0];
  const float* W_emb  = (const float*)d_in[1];
  const float* pos    = (const float*)d_in[2];
  const float* ln1_s  = (const float*)d_in[3];
  const float* ln1_b  = (const float*)d_in[4];
  const float* qkv_w  = (const float*)d_in[5];
  const float* proj_w = (const float*)d_in[6];
  const float* ln2_s  = (const float*)d_in[7];
  const float* ln2_b  = (const float*)d_in[8];
  const float* gate_w = (const float*)d_in[9];
  const float* up_w   = (const float*)d_in[10];
  const float* down_w = (const float*)d_in[11];
  const float* lnf_s  = (const float*)d_in[12];
  const float* lnf_b  = (const float*)d_in[13];
  float* out = (float*)d_out;

  char* p = (char*)d_ws;
  auto alloc = [&](size_t bytes) { char* q = p; p += (bytes + 255) & ~255ULL; return q; };
  float* x      = (float*)alloc((size_t)ROWS * E_SZ * 4);
  float* statsA = (float*)alloc((size_t)ROWS * 32 * 4);
  float* statsB = (float*)alloc((size_t)ROWS * 32 * 4);
  __hip_bfloat16* qkv_bf = (__hip_bfloat16*)alloc((size_t)ROWS * 3 * E_SZ * 2);
  __hip_bfloat16* h_bf  = (__hip_bfloat16*)alloc((size_t)ROWS * E_SZ * 2);
  __hip_bfloat16* o_bf  = (__hip_bfloat16*)alloc((size_t)ROWS * E_SZ * 2);
  __hip_bfloat16* g_bf  = (__hip_bfloat16*)alloc((size_t)ROWS * HID_PAD * 2);
  __hip_bfloat16* Wb    = (__hip_bfloat16*)alloc((size_t)V_PAD * E_SZ * 2);
  __hip_bfloat16* qkvwb = (__hip_bfloat16*)alloc((size_t)L_N * 3 * E_SZ * E_SZ * 2);
  __hip_bfloat16* projwb= (__hip_bfloat16*)alloc((size_t)L_N * E_SZ * E_SZ * 2);
  __hip_bfloat16* guwb  = (__hip_bfloat16*)alloc((size_t)L_N * 2816 * E_SZ * 2);
  __hip_bfloat16* downwb= (__hip_bfloat16*)alloc((size_t)L_N * E_SZ * HID_PAD * 2);

  // ---- weight prep ----
  convert_wemb<<<(V_PAD * E_SZ / 8 + 255) / 256, 256, 0, stream>>>(W_emb, Wb);
  transp_convert<<<dim3(3 * E_SZ / 32, E_SZ / 32, L_N), 256, 0, stream>>>(
      qkv_w, qkvwb, E_SZ, 3 * E_SZ, E_SZ, 3 * E_SZ);
  transp_convert<<<dim3(E_SZ / 32, E_SZ / 32, L_N), 256, 0, stream>>>(
      proj_w, projwb, E_SZ, E_SZ, E_SZ, E_SZ);
  gu_prep<<<dim3(HID_PAD / 32, E_SZ / 32, L_N), 256, 0, stream>>>(gate_w, up_w, guwb);
  transp_convert<<<dim3(E_SZ / 32, HID_PAD / 32, L_N), 256, 0, stream>>>(
      down_w, downwb, HID_SZ, E_SZ, HID_PAD, E_SZ);

  embed_kernel<<<ROWS, 128, 0, stream>>>(idx, W_emb, pos, x, statsA);

  for (int l = 0; l < L_N; ++l) {
    gemm64ln<1><<<dim3(3 * E_SZ / 64, ROWS / 64), 256, 0, stream>>>(
        x, qkvwb + (size_t)l * 3 * E_SZ * E_SZ, qkv_bf, statsA,
        ln1_s + l * E_SZ, ln1_b + l * E_SZ, 3 * E_SZ, E_SZ);
    attn_mfma_kernel<<<B_SZ * H_N * (T_SZ / 64), 256, 0, stream>>>(qkv_bf, o_bf);
    gemm64<<<dim3(E_SZ / 64, ROWS / 64), 256, 0, stream>>>(
        o_bf, projwb + (size_t)l * E_SZ * E_SZ, x, x, statsB, E_SZ, E_SZ);
    gemm64ln<3><<<dim3(2816 / 64, ROWS / 64), 256, 0, stream>>>(
        x, guwb + (size_t)l * 2816 * E_SZ, g_bf, statsB,
        ln2_s + l * E_SZ, ln2_b + l * E_SZ, 2816, E_SZ);
    gemm64<<<dim3(E_SZ / 64, ROWS / 64), 256, 0, stream>>>(
        g_bf, downwb + (size_t)l * E_SZ * HID_PAD, x, x, statsA, E_SZ, HID_PAD);
  }

  ln_from_stats<<<ROWS, 256, 0, stream>>>(x, statsA, lnf_s, lnf_b, h_bf);
  head_gemm<<<dim3(V_PAD / 128, 16), 256, 0, stream>>>(h_bf, Wb, out, V_SZ, E_SZ);
}